// Round 1
// baseline (1315.967 us; speedup 1.0000x reference)
//
#include <hip/hip_runtime.h>

#define B_ROWS 65536

typedef __attribute__((ext_vector_type(8))) __bf16 bf16x8;
typedef __attribute__((ext_vector_type(8))) _Float16 f16x8;
typedef __attribute__((ext_vector_type(4))) float f32x4;
typedef __attribute__((ext_vector_type(8))) unsigned short u16x8;

__device__ __forceinline__ unsigned short f2bf(float f) {
  unsigned int u = __float_as_uint(f);
  u += 0x7fffu + ((u >> 16) & 1u);   // RNE
  return (unsigned short)(u >> 16);
}

__device__ __forceinline__ float elu_f(float v) {
  return v > 0.f ? v : __expf(v) - 1.f;
}

__device__ __forceinline__ void async_ld16(const void* g, void* l) {
  __builtin_amdgcn_global_load_lds(
      (const __attribute__((address_space(1))) void*)g,
      (__attribute__((address_space(3))) void*)l, 16, 0, 0);
}

// ---------------- fused gating MLP (f16 MFMA, f32 acc) + z->bf16 convert ----
// 512 blocks x 128 rows. W tiles staged whole in LDS (padded stride 136 f16).
// Activations stay in LDS; logits w written f32. f16 keeps w error ~0.1% rel.
#define GP 136  // padded LDS row stride in f16 (272 B -> 2-way banks = free)

__global__ __launch_bounds__(256) void gating_mfma(
    const float* __restrict__ z, const int* __restrict__ idx,
    const float* __restrict__ Wg1, const float* __restrict__ bg1,
    const float* __restrict__ Wg2, const float* __restrict__ bg2,
    const float* __restrict__ Wg3, const float* __restrict__ bg3,
    float* __restrict__ wq, unsigned short* __restrict__ zb) {
  __shared__ _Float16 Ab[128 * GP];   // activations [row][k]
  __shared__ _Float16 Wb[128 * GP];   // W^T [n][k]
  __shared__ int idx_l[128];

  const int tid = threadIdx.x;
  const int lane = tid & 63, wave = tid >> 6;
  const int wr = wave >> 1, wc = wave & 1;
  const int lhi = lane >> 4, llo = lane & 15;
  const size_t row0 = (size_t)blockIdx.x * 128;

  if (tid < 128) idx_l[tid] = idx[tid];
  // stage W1^T: Wg1[k][n] -> Wb[n][k] f16
  for (int i = tid; i < 16384; i += 256) {
    const int k = i >> 7, n = i & 127;
    Wb[n * GP + k] = (_Float16)Wg1[i];
  }
  // fold in z -> bf16 convert for this block's 128 rows (warms L2 for gather)
  {
    const float* zr = z + row0 * 512;
    unsigned short* zo = zb + row0 * 512;
    for (int i = tid; i < 8192; i += 256) {
      const size_t off = (size_t)i * 8;
      float4 a = *(const float4*)(zr + off);
      float4 b = *(const float4*)(zr + off + 4);
      u16x8 r;
      r[0] = f2bf(a.x); r[1] = f2bf(a.y); r[2] = f2bf(a.z); r[3] = f2bf(a.w);
      r[4] = f2bf(b.x); r[5] = f2bf(b.y); r[6] = f2bf(b.z); r[7] = f2bf(b.w);
      *(u16x8*)(zo + off) = r;
    }
  }
  __syncthreads();
  // gather + convert x tile: Ab[r][c] = z[row0+r][idx[c]]
  for (int i = tid; i < 16384; i += 256) {
    const int r = i >> 7, c = i & 127;
    Ab[r * GP + c] = (_Float16)z[(row0 + r) * 512 + idx_l[c]];
  }
  __syncthreads();

  const f32x4 vzero = {0.f, 0.f, 0.f, 0.f};

  // ---- layer 1: [128x128] @ [128x128] ----
  f32x4 C[4][4];
#pragma unroll
  for (int i = 0; i < 4; i++)
#pragma unroll
    for (int j = 0; j < 4; j++) C[i][j] = vzero;
#pragma unroll
  for (int ks = 0; ks < 4; ks++) {
    f16x8 av[4], bv[4];
#pragma unroll
    for (int fm = 0; fm < 4; fm++)
      av[fm] = *(const f16x8*)&Ab[(wr * 64 + fm * 16 + llo) * GP + ks * 32 + lhi * 8];
#pragma unroll
    for (int fn = 0; fn < 4; fn++)
      bv[fn] = *(const f16x8*)&Wb[(wc * 64 + fn * 16 + llo) * GP + ks * 32 + lhi * 8];
#pragma unroll
    for (int fm = 0; fm < 4; fm++)
#pragma unroll
      for (int fn = 0; fn < 4; fn++)
        C[fm][fn] = __builtin_amdgcn_mfma_f32_16x16x32_f16(av[fm], bv[fn], C[fm][fn], 0, 0, 0);
  }
  __syncthreads();  // all reads of Ab/Wb done
  // g1 = elu(C + bg1) -> Ab ; stage W2^T -> Wb
#pragma unroll
  for (int fm = 0; fm < 4; fm++)
#pragma unroll
    for (int fn = 0; fn < 4; fn++) {
      const int col = wc * 64 + fn * 16 + llo;
      const float bb = bg1[col];
#pragma unroll
      for (int r = 0; r < 4; r++) {
        const int row = wr * 64 + fm * 16 + lhi * 4 + r;
        Ab[row * GP + col] = (_Float16)elu_f(C[fm][fn][r] + bb);
      }
    }
  for (int i = tid; i < 16384; i += 256) {
    const int k = i >> 7, n = i & 127;
    Wb[n * GP + k] = (_Float16)Wg2[i];
  }
  __syncthreads();

  // ---- layer 2 ----
#pragma unroll
  for (int i = 0; i < 4; i++)
#pragma unroll
    for (int j = 0; j < 4; j++) C[i][j] = vzero;
#pragma unroll
  for (int ks = 0; ks < 4; ks++) {
    f16x8 av[4], bv[4];
#pragma unroll
    for (int fm = 0; fm < 4; fm++)
      av[fm] = *(const f16x8*)&Ab[(wr * 64 + fm * 16 + llo) * GP + ks * 32 + lhi * 8];
#pragma unroll
    for (int fn = 0; fn < 4; fn++)
      bv[fn] = *(const f16x8*)&Wb[(wc * 64 + fn * 16 + llo) * GP + ks * 32 + lhi * 8];
#pragma unroll
    for (int fm = 0; fm < 4; fm++)
#pragma unroll
      for (int fn = 0; fn < 4; fn++)
        C[fm][fn] = __builtin_amdgcn_mfma_f32_16x16x32_f16(av[fm], bv[fn], C[fm][fn], 0, 0, 0);
  }
  __syncthreads();
  // g2 = elu(C + bg2) -> Ab ; stage W3^T (padded to 16 cols) -> Wb
#pragma unroll
  for (int fm = 0; fm < 4; fm++)
#pragma unroll
    for (int fn = 0; fn < 4; fn++) {
      const int col = wc * 64 + fn * 16 + llo;
      const float bb = bg2[col];
#pragma unroll
      for (int r = 0; r < 4; r++) {
        const int row = wr * 64 + fm * 16 + lhi * 4 + r;
        Ab[row * GP + col] = (_Float16)elu_f(C[fm][fn][r] + bb);
      }
    }
  for (int i = tid; i < 2048; i += 256) {
    const int k = i >> 4, n = i & 15;
    Wb[n * GP + k] = (n < 8) ? (_Float16)Wg3[k * 8 + n] : (_Float16)0.f;
  }
  __syncthreads();

  // ---- layer 3: [128x128] @ [128x8] (only wc==0 waves store) ----
  f32x4 C3[4];
#pragma unroll
  for (int i = 0; i < 4; i++) C3[i] = vzero;
#pragma unroll
  for (int ks = 0; ks < 4; ks++) {
    f16x8 av[4];
#pragma unroll
    for (int fm = 0; fm < 4; fm++)
      av[fm] = *(const f16x8*)&Ab[(wr * 64 + fm * 16 + llo) * GP + ks * 32 + lhi * 8];
    const f16x8 bv = *(const f16x8*)&Wb[llo * GP + ks * 32 + lhi * 8];
#pragma unroll
    for (int fm = 0; fm < 4; fm++)
      C3[fm] = __builtin_amdgcn_mfma_f32_16x16x32_f16(av[fm], bv, C3[fm], 0, 0, 0);
  }
  if (wc == 0 && llo < 8) {
    const float bb = bg3[llo];
#pragma unroll
    for (int fm = 0; fm < 4; fm++)
#pragma unroll
      for (int r = 0; r < 4; r++) {
        const size_t row = row0 + wr * 64 + fm * 16 + lhi * 4 + r;
        wq[row * 8 + llo] = C3[fm][r] + bb;
      }
  }
}

// ---------------- W[e][i][o] f32 -> Wt[e][o][i] bf16 (B^T layout) ----------
__global__ __launch_bounds__(256) void transpose_w(
    const float* __restrict__ W1, const float* __restrict__ W2,
    const float* __restrict__ W3, unsigned short* __restrict__ Wt) {
  __shared__ float t[32][33];
  const int le = blockIdx.z;  // layer*8 + e, 0..23
  const float* W = (le < 8) ? W1 : (le < 16) ? W2 : W3;
  const size_t eoff = (size_t)(le & 7) * 262144;
  unsigned short* O = Wt + (size_t)le * 262144;
  const int i0 = blockIdx.y * 32, o0 = blockIdx.x * 32;
  const int tx = threadIdx.x & 31, ty = threadIdx.x >> 5;
#pragma unroll
  for (int s = 0; s < 4; s++)
    t[ty + s * 8][tx] = W[eoff + (size_t)(i0 + ty + s * 8) * 512 + o0 + tx];
  __syncthreads();
#pragma unroll
  for (int s = 0; s < 4; s++)
    O[(size_t)(o0 + ty + s * 8) * 512 + i0 + tx] = f2bf(t[tx][ty + s * 8]);
}

// ---------------- soft-MoE expert layer: out = sum_e w_e*(X@W_e + b_e) -----
// BM=256 x BN=128 tile, BK=64, 512 threads (8 waves, 4Mx2N, each 64x64).
// Triple-buffered LDS staging via global_load_lds(16B) with XOR chunk swizzle;
// counted-vmcnt pipeline (T3+T4): step t reads buf[t%3], stages tile t+2,
// end-of-step s_waitcnt vmcnt(6) retires exactly the next tile (never drains
// to 0 in steady state). setprio(1) around each 16-MFMA cluster (T5).
// Per-expert AGPR partial combined into fp32 C with per-row gate weight.
template <bool ELU, bool OUTBF>
__global__ __launch_bounds__(512, 2) void expert_layer(
    const unsigned short* __restrict__ X,   // 65536 x 512 bf16
    const unsigned short* __restrict__ Wt,  // 8 x 512 x 512 bf16 [e][o][i]
    const float* __restrict__ bias,         // 8 x 512 f32 [e][o]
    const float* __restrict__ wq,           // 65536 x 8 f32
    void* __restrict__ Out) {
  // 3 x (A[256][64] 32KB + B[128][64] 16KB) = 144KB
  __shared__ __align__(16) short lds[3 * 24576];
  __shared__ __align__(16) float w_lds[8 * 256];     // [e][row] 8KB
  __shared__ __align__(16) float bias_lds[8 * 128];  // [e][col] 4KB

  const int tid = threadIdx.x;               // 0..511
  const int lane = tid & 63;
  const int wave = tid >> 6;                 // 0..7
  const int wr = wave >> 1, wc = wave & 1;   // 4M x 2N
  const int lhi = lane >> 4, llo = lane & 15;

  // XCD-aware swizzle: 1024 blocks = 8 xcd * 32 mb * 4 nb, nb outermost so
  // concurrent blocks on an XCD share the same weight panel in L2.
  const int g = blockIdx.x;
  const int xcd = g & 7;
  const int sg = g >> 3;                     // 0..127
  const int nb = sg >> 5;                    // 0..3
  const int mb = xcd * 32 + (sg & 31);       // 0..255
  const size_t row0 = (size_t)mb * 256;
  const int col0 = nb * 128;

  for (int i = tid; i < 2048; i += 512) {
    const int e = i >> 8, r = i & 255;
    w_lds[i] = wq[(row0 + r) * 8 + e];
  }
  for (int i = tid; i < 1024; i += 512) {
    const int e = i >> 7, r = i & 127;
    bias_lds[i] = bias[e * 512 + col0 + r];
  }
  __syncthreads();  // drain fill loads so in-loop vmcnt bookkeeping is exact

  // staging: 512 threads = 64 rows x 8 chunks(16B) per round; swizzled source
  const int srow = tid >> 3;                      // 0..63
  const int cgo = ((tid & 7) ^ (srow & 7)) << 4;  // swizzled global 16B chunk
  const char* Ag = (const char*)X + (row0 + srow) * 1024 + cgo;
  const char* Bg = (const char*)Wt + (size_t)(col0 + srow) * 1024 + cgo;

  // half h=0: A rows 0..127 (2 loads) + B rows 0..63; h=1: the rest. 3+3/tile.
  auto stage = [&](int sbuf, int e, int kt, int h) {
    const char* ga = Ag + kt * 128;
    const char* gb = Bg + (size_t)e * 524288 + kt * 128;
    char* lp = (char*)lds + sbuf + tid * 16;
    if (h == 0) {
      async_ld16(ga,          lp);            // A rows 0..63
      async_ld16(ga + 65536,  lp + 8192);     // A rows 64..127
      async_ld16(gb,          lp + 32768);    // B rows 0..63
    } else {
      async_ld16(ga + 131072, lp + 16384);    // A rows 128..191
      async_ld16(ga + 196608, lp + 24576);    // A rows 192..255
      async_ld16(gb + 65536,  lp + 40960);    // B rows 64..127
    }
  };

  int b0 = 0, b1 = 49152, b2 = 98304;  // byte offsets: cur, next, stage-target

  // prologue: tile0 -> b0, tile1 -> b1 (12 loads in flight)
  stage(b0, 0, 0, 0); stage(b0, 0, 0, 1);
  stage(b1, 0, 1, 0); stage(b1, 0, 1, 1);
  asm volatile("s_waitcnt vmcnt(6)" ::: "memory");  // tile0 complete
  __builtin_amdgcn_s_barrier();

  const int rsw = llo & 7;                    // frag-read swizzle key
  const int slot0 = (lhi ^ rsw) << 4;         // k = 0..31
  const int slot1 = ((4 + lhi) ^ rsw) << 4;   // k = 32..63
  const int aRow = (wr * 64 + llo) * 128;           // + fm*2048
  const int bRow = 32768 + (wc * 64 + llo) * 128;   // + fn*2048

  const f32x4 vzero = {0.f, 0.f, 0.f, 0.f};
  f32x4 C[4][4];
#pragma unroll
  for (int i = 0; i < 4; i++)
#pragma unroll
    for (int j = 0; j < 4; j++) C[i][j] = vzero;

  int t = 0;
#pragma unroll 1
  for (int e = 0; e < 8; e++) {
    f32x4 acc[4][4];
#pragma unroll
    for (int i = 0; i < 4; i++)
#pragma unroll
      for (int j = 0; j < 4; j++) acc[i][j] = vzero;

#pragma unroll 1
    for (int kt = 0; kt < 8; kt++, t++) {
      const int t2 = t + 2;
      const bool more = t2 < 64;
      const int e2 = t2 >> 3, kt2 = t2 & 7;
      const char* base = (const char*)lds + b0;

      // ---- phase 0 (k = 0..31): ds_read + issue half0(t+2) + MFMA ----
      {
        bf16x8 av[4], bv[4];
#pragma unroll
        for (int fm = 0; fm < 4; fm++)
          av[fm] = *(const bf16x8*)(base + aRow + fm * 2048 + slot0);
#pragma unroll
        for (int fn = 0; fn < 4; fn++)
          bv[fn] = *(const bf16x8*)(base + bRow + fn * 2048 + slot0);
        if (more) stage(b2, e2, kt2, 0);
        __builtin_amdgcn_s_barrier();
        asm volatile("s_waitcnt lgkmcnt(0)" ::: "memory");
        __builtin_amdgcn_s_setprio(1);
#pragma unroll
        for (int fm = 0; fm < 4; fm++)
#pragma unroll
          for (int fn = 0; fn < 4; fn++)
            acc[fm][fn] = __builtin_amdgcn_mfma_f32_16x16x32_bf16(
                av[fm], bv[fn], acc[fm][fn], 0, 0, 0);
        __builtin_amdgcn_s_setprio(0);
        __builtin_amdgcn_s_barrier();
      }

      // ---- phase 1 (k = 32..63): ds_read + issue half1(t+2) + MFMA ----
      {
        bf16x8 av[4], bv[4];
#pragma unroll
        for (int fm = 0; fm < 4; fm++)
          av[fm] = *(const bf16x8*)(base + aRow + fm * 2048 + slot1);
#pragma unroll
        for (int fn = 0; fn < 4; fn++)
          bv[fn] = *(const bf16x8*)(base + bRow + fn * 2048 + slot1);
        if (more) stage(b2, e2, kt2, 1);
        __builtin_amdgcn_s_barrier();
        asm volatile("s_waitcnt lgkmcnt(0)" ::: "memory");
        __builtin_amdgcn_s_setprio(1);
#pragma unroll
        for (int fm = 0; fm < 4; fm++)
#pragma unroll
          for (int fn = 0; fn < 4; fn++)
            acc[fm][fn] = __builtin_amdgcn_mfma_f32_16x16x32_bf16(
                av[fm], bv[fn], acc[fm][fn], 0, 0, 0);
        __builtin_amdgcn_s_setprio(0);
        // retire tile t+1 (oldest 6 of 12 outstanding); never drains mid-loop
        if (t < 62)
          asm volatile("s_waitcnt vmcnt(6)" ::: "memory");
        else
          asm volatile("s_waitcnt vmcnt(0)" ::: "memory");
        __builtin_amdgcn_s_barrier();
      }
      const int tmp = b0; b0 = b1; b1 = b2; b2 = tmp;  // rotate buffers
    }

    // fp32 combine: C += w[row,e] * P_e (register-only, no barrier needed)
#pragma unroll
    for (int fm = 0; fm < 4; fm++) {
      const f32x4 wv =
          *(const f32x4*)(w_lds + e * 256 + wr * 64 + fm * 16 + lhi * 4);
#pragma unroll
      for (int fn = 0; fn < 4; fn++)
#pragma unroll
        for (int r = 0; r < 4; r++) C[fm][fn][r] += wv[r] * acc[fm][fn][r];
    }
  }

  // bias: C += sum_e w[row,e] * b[e,col]  (once per block)
#pragma unroll
  for (int e = 0; e < 8; e++) {
    f32x4 wv[4];
#pragma unroll
    for (int fm = 0; fm < 4; fm++)
      wv[fm] = *(const f32x4*)(w_lds + e * 256 + wr * 64 + fm * 16 + lhi * 4);
#pragma unroll
    for (int fn = 0; fn < 4; fn++) {
      const float bb = bias_lds[e * 128 + wc * 64 + fn * 16 + llo];
#pragma unroll
      for (int fm = 0; fm < 4; fm++)
#pragma unroll
        for (int r = 0; r < 4; r++) C[fm][fn][r] += wv[fm][r] * bb;
    }
  }

  // epilogue: ELU + store (bf16 h or f32 final)
#pragma unroll
  for (int fm = 0; fm < 4; fm++)
#pragma unroll
    for (int fn = 0; fn < 4; fn++)
#pragma unroll
      for (int r = 0; r < 4; r++) {
        float v = C[fm][fn][r];
        if (ELU) v = elu_f(v);
        const size_t orow = row0 + wr * 64 + fm * 16 + lhi * 4 + r;
        const int ocol = col0 + wc * 64 + fn * 16 + llo;
        if (OUTBF)
          ((unsigned short*)Out)[orow * 512 + ocol] = f2bf(v);
        else
          ((float*)Out)[orow * 512 + ocol] = v;
      }
}

extern "C" void kernel_launch(void* const* d_in, const int* in_sizes, int n_in,
                              void* d_out, int out_size, void* d_ws,
                              size_t ws_size, hipStream_t stream) {
  (void)in_sizes; (void)n_in; (void)out_size; (void)ws_size;
  const float* z   = (const float*)d_in[0];
  const int*   idx = (const int*)d_in[1];
  const float* Wg1 = (const float*)d_in[2];
  const float* bg1 = (const float*)d_in[3];
  const float* Wg2 = (const float*)d_in[4];
  const float* bg2 = (const float*)d_in[5];
  const float* Wg3 = (const float*)d_in[6];
  const float* bg3 = (const float*)d_in[7];
  const float* W1  = (const float*)d_in[8];
  const float* b1  = (const float*)d_in[9];
  const float* W2  = (const float*)d_in[10];
  const float* b2  = (const float*)d_in[11];
  const float* W3  = (const float*)d_in[12];
  const float* b3  = (const float*)d_in[13];

  // workspace layout:
  //   [0,2M)      w gate logits f32
  //   [2M,66M)    zb  (z bf16)        -- layer2 output h2 aliases here
  //   [66M,130M)  h1 bf16
  //   [130M,142M) Wt: 3x8x512x512 bf16 [l][e][o][i]
  char* ws = (char*)d_ws;
  float* wq = (float*)ws;
  unsigned short* zb = (unsigned short*)(ws + (size_t)(2u << 20));
  unsigned short* h1 = (unsigned short*)(ws + (size_t)(66u << 20));
  unsigned short* Wt = (unsigned short*)(ws + (size_t)(130u << 20));
  unsigned short* h2 = zb;        // zb dead after layer1

  gating_mfma<<<dim3(512), dim3(256), 0, stream>>>(
      z, idx, Wg1, bg1, Wg2, bg2, Wg3, bg3, wq, zb);
  transpose_w<<<dim3(16, 16, 24), dim3(256), 0, stream>>>(W1, W2, W3, Wt);

  expert_layer<true, true><<<dim3(1024), dim3(512), 0, stream>>>(
      zb, Wt, b1, wq, (void*)h1);
  expert_layer<true, true><<<dim3(1024), dim3(512), 0, stream>>>(
      h1, Wt + (size_t)8 * 262144, b2, wq, (void*)h2);
  expert_layer<false, false><<<dim3(1024), dim3(512), 0, stream>>>(
      h2, Wt + (size_t)16 * 262144, b3, wq, d_out);
}